// Round 1
// 532.882 us; speedup vs baseline: 1.0140x; 1.0140x over previous
//
#include <hip/hip_runtime.h>
#include <hip/hip_bf16.h>

// N=65536 points, H=256, 4 hidden layers, ReLU MLP -> (psi,p).
// ReLU => piecewise linear => Hessians vanish; f = p_x, g = p_y (RHO=1).
// Pipeline:
//   1) fp32 forward replicating np/BLAS arithmetic BIT-EXACTLY (v11 base).
//      v20: k-loop chunked by 4 (was unroll 2). Rationale: SMEM returns are
//      OOO -> compiler drains lgkmcnt(0) before first weight use; unroll-2
//      gave only 64 FMA-issue cyc per ~300cyc scalar drain -> VALUBusy 68%
//      (4x64/364 = 0.70, matches). Chunk-4 = 4x s_load_dwordx16 (64 SGPR)
//      + 8 ds_read per drain -> 128 FMA cyc/drain -> predicted saturation.
//      Per-accumulator fmaf order stays k-ascending: BIT-IDENTICAL output.
//   2) v19 fused tangent kernel (UNMODIFIED):
//      a) MFMA operand swap mfma(bf,af,acc) -> transposed D layout ->
//         write-back = 16 ds_write_b64 instead of 64 ds_write_b16;
//      b) finalize = one MFMA chain (Wout rounded to f16: ~1e-5, margin 6.5x).
// Workspace: masks 5x2MB | Wt 512KB

#define NPTS 65536
#define HDIM 256

typedef _Float16 half8_t __attribute__((ext_vector_type(8)));
typedef _Float16 half4_t __attribute__((ext_vector_type(4)));
typedef float floatx4 __attribute__((ext_vector_type(4)));

// ---------------------------------------------------------------- fused fp32 forward (np/BLAS-exact)
__global__ void __launch_bounds__(1024) fwd_fused_kernel(
    const float* __restrict__ x, const float* __restrict__ y, const float* __restrict__ t,
    const float* __restrict__ Win, const float* __restrict__ b_in,
    const float* __restrict__ Wh, const float* __restrict__ b_h,
    const float* __restrict__ Wout, const float* __restrict__ b_out,
    unsigned char* __restrict__ masks, float* __restrict__ out) {
  constexpr int SH = 257;              // odd stride: conflict-free b32
  __shared__ float hT[128 * SH];       // [pt][k]  131584 B
  __shared__ float pscr[16][132];      // wave partials for p (8448 B)

  const int tid = threadIdx.x;
  const int lane = tid & 63;
  const int w = __builtin_amdgcn_readfirstlane(tid >> 6);       // wave id 0..15
  const int c0 = w * 16;                                        // 16-col group
  const int p0 = blockIdx.x * 128;
  const int pA = p0 + lane;            // point A
  const int pB = p0 + 64 + lane;       // point B

  // ---- layer 1: dot = z @ Win (k ascending: x,y,t), then + b_in  [bit-exact]
  {
    float xa = x[pA], ya = y[pA], ta = t[pA];
    float xb = x[pB], yb = y[pB], tb = t[pB];
    unsigned ma = 0, mb = 0;
#pragma unroll
    for (int e = 0; e < 16; ++e) {
      int c = c0 + e;                  // uniform -> Win reads are scalar
      float w0 = Win[c], w1 = Win[256 + c], w2 = Win[512 + c], bb = b_in[c];
      float da = fmaf(xa, w0, 0.f);
      da = fmaf(ya, w1, da);
      da = fmaf(ta, w2, da);
      float aa = da + bb;
      bool posa = aa > 0.f;
      hT[lane * SH + c] = posa ? aa : 0.f;
      ma |= (posa ? 1u : 0u) << e;
      float db = fmaf(xb, w0, 0.f);
      db = fmaf(yb, w1, db);
      db = fmaf(tb, w2, db);
      float ab = db + bb;
      bool posb = ab > 0.f;
      hT[(64 + lane) * SH + c] = posb ? ab : 0.f;
      mb |= (posb ? 1u : 0u) << e;
    }
    *(unsigned short*)(masks + (size_t)pA * 32 + w * 2) = (unsigned short)ma;
    *(unsigned short*)(masks + (size_t)pB * 32 + w * 2) = (unsigned short)mb;
  }
  __syncthreads();

  // ---- hidden layers: single fp32 accumulator per element, k ascending, fmaf
  // v20: chunk-4 software structure. All loads (8 ds_read + 4 s_load_dwordx16)
  // issue before the 128-FMA block so one lgkmcnt drain covers 4 k-steps.
  for (int l = 0; l < 4; ++l) {
    const float* Wl = Wh + (size_t)l * 65536 + c0;   // + uniform col offset
    float accA[16] = {};
    float accB[16] = {};
#pragma unroll 1
    for (int k0 = 0; k0 < 256; k0 += 4) {
      float hAv[4], hBv[4];
#pragma unroll
      for (int u = 0; u < 4; ++u) {
        hAv[u] = hT[lane * SH + k0 + u];          // per-lane LDS, conflict-free
        hBv[u] = hT[(64 + lane) * SH + k0 + u];
      }
#pragma unroll
      for (int u = 0; u < 4; ++u) {
        const float* wr = Wl + (k0 + u) * 256;    // wave-uniform -> s_load_dwordx16
#pragma unroll
        for (int e = 0; e < 16; ++e) {
          float wv = wr[e];
          accA[e] = fmaf(hAv[u], wv, accA[e]);    // k-ascending per acc: bit-exact
          accB[e] = fmaf(hBv[u], wv, accB[e]);
        }
      }
    }
    __syncthreads();                   // all hT reads done before overwrite
    unsigned ma = 0, mb = 0;
    float hnA[16], hnB[16];
#pragma unroll
    for (int e = 0; e < 16; ++e) {
      float bb = b_h[l * 256 + c0 + e];
      float aa = accA[e] + bb;
      bool posa = aa > 0.f;
      hnA[e] = posa ? aa : 0.f;
      ma |= (posa ? 1u : 0u) << e;
      float ab = accB[e] + bb;
      bool posb = ab > 0.f;
      hnB[e] = posb ? ab : 0.f;
      mb |= (posb ? 1u : 0u) << e;
    }
    *(unsigned short*)(masks + ((size_t)(l + 1) * NPTS + pA) * 32 + w * 2) =
        (unsigned short)ma;
    *(unsigned short*)(masks + ((size_t)(l + 1) * NPTS + pB) * 32 + w * 2) =
        (unsigned short)mb;
#pragma unroll
    for (int e = 0; e < 16; ++e) {
      hT[lane * SH + c0 + e] = hnA[e];
      hT[(64 + lane) * SH + c0 + e] = hnB[e];
    }
    __syncthreads();
  }

  // ---- p = h5 . Wout[:,1] + b_out[1]
  {
    float sA = 0.f, sB = 0.f;
#pragma unroll
    for (int e = 0; e < 16; ++e) {
      float wv = Wout[2 * (c0 + e) + 1];
      sA = fmaf(hT[lane * SH + c0 + e], wv, sA);
      sB = fmaf(hT[(64 + lane) * SH + c0 + e], wv, sB);
    }
    pscr[w][lane] = sA;
    pscr[w][64 + lane] = sB;
  }
  __syncthreads();
  if (tid < 128) {
    float s2 = 0.f;
#pragma unroll
    for (int g = 0; g < 16; ++g) s2 += pscr[g][tid];
    out[2 * NPTS + p0 + tid] = s2 + b_out[1];
  }
}

// ---------------------------------------------------------------- prep: Wh fp32 [l][k][n] -> f16 [l][n][k]
__global__ void __launch_bounds__(256) prep_weights_kernel(
    const float* __restrict__ Wh, _Float16* __restrict__ Wt) {
  int i = blockIdx.x * 256 + threadIdx.x;   // 0..262143
  int l = i >> 16;
  int rem = i & 65535;
  int k = rem >> 8, n = rem & 255;
  Wt[(size_t)(l << 16) + n * 256 + k] = (_Float16)Wh[i];
}

// ---------------------------------------------------------------- fused tangent chain (init + 4 layers + finalize)
// Block: 256 thr = 4 waves. 32 points -> 64 rows (0..31 x-tangent, 32..63 y).
// Tile M=64 x N=256; wave wn owns 64 rows x 64 cols. T lives in Apan (f16).
// v19: mfma(bf, af, acc) OPERAND SWAP -> D[row = n-local quad*4+reg]
// [col = m-local l15]: lane holds 4 consecutive n for one row m ->
// write-back is 16 x ds_write_b64. Finalize = MFMA chain with zero-padded
// f16 Wout B-fragment. B staging = v15 wave-private (barrier-free).
// mfma_f32_16x16x32_f16: A[m=lane&15][k=quad*8+j], B[k=quad*8+j][n=lane&15],
//                        D[row=quad*4+reg][col=lane&15]  (verified layouts)
__global__ void __launch_bounds__(256, 2) tangent_fused_kernel(
    const float* __restrict__ Win,
    const _Float16* __restrict__ Wt,          // [l][n][k] (pre-transposed)
    const unsigned int* __restrict__ maskDw,  // [5][NPTS][8] dwords
    const float* __restrict__ Wout, float* __restrict__ out) {
  constexpr int SA = 264;   // A row stride (halves): 256 + 8 pad
  constexpr int SB = 72;    // B row stride (halves): 64 + 8 pad
  __shared__ alignas(16) _Float16 Apan[64 * SA];        // 33792 B
  __shared__ alignas(16) _Float16 Bpan[4][64 * SB];     // 36864 B
  __shared__ unsigned int smask[5 * 256];               // 5120 B

  const int tid = threadIdx.x;
  const int lane = tid & 63;
  const int wn = tid >> 6;          // wave = 64-col group
  const int l15 = lane & 15, quad = lane >> 4;
  const int p0 = blockIdx.x * 32;   // 32 points per block

  // ---- stage all 5 mask layers (32 pts x 8 dw each)
#pragma unroll
  for (int i = 0; i < 5; ++i)
    smask[i * 256 + tid] = maskDw[(size_t)i * NPTS * 8 + (size_t)p0 * 8 + tid];
  __syncthreads();

  // ---- init T1 into Apan: row<32 -> x-tangent (Win row 0), row>=32 -> y (row 1)
#pragma unroll
  for (int i = 0; i < 8; ++i) {
    int g = tid + 256 * i;          // 0..2047 col-groups of 8
    int row = g >> 5, cg = g & 31;
    int c0 = cg * 8, pt = row & 31, tg = row >> 5;
    unsigned dw = smask[pt * 8 + (c0 >> 5)];
    half8_t v;
#pragma unroll
    for (int e = 0; e < 8; ++e) {
      bool m = (dw >> ((cg & 3) * 8 + e)) & 1;
      v[e] = m ? (_Float16)Win[tg * 256 + c0 + e] : (_Float16)0.f;
    }
    *(half8_t*)&Apan[row * SA + c0] = v;
  }
  __syncthreads();                  // Apan init visible to all waves

  // ---- 4 layers: acc = A @ W_l (computed transposed), gate, back into Apan
  for (int l = 0; l < 4; ++l) {
    const _Float16* Bw = Wt + (size_t)l * 65536 + (size_t)(wn * 64) * 256;
    _Float16* Bp = &Bpan[wn][0];
    floatx4 acc[4][4] = {};   // [mi][nj], element = D[n-local][m-local]
#pragma unroll
    for (int kp = 0; kp < 4; ++kp) {
      // wave-private B staging (no barrier; within-wave lgkmcnt ordering)
#pragma unroll
      for (int i = 0; i < 8; ++i) {
        int idx = lane + 64 * i;    // 0..511 half8 segs
        int row = idx >> 3, seg = idx & 7;
        *(half8_t*)&Bp[row * SB + seg * 8] =
            *(const half8_t*)(Bw + (size_t)row * 256 + kp * 64 + seg * 8);
      }
#pragma unroll
      for (int ks = 0; ks < 2; ++ks) {
        half8_t af[4], bf[4];
#pragma unroll
        for (int mi = 0; mi < 4; ++mi)
          af[mi] = *(const half8_t*)&Apan[(mi * 16 + l15) * SA + kp * 64 + ks * 32 + quad * 8];
#pragma unroll
        for (int nj = 0; nj < 4; ++nj)
          bf[nj] = *(const half8_t*)&Bp[(nj * 16 + l15) * SB + ks * 32 + quad * 8];
        // SWAPPED operands: same products/order (bit-identical values),
        // transposed D layout (lane = one T-row m, 4 consecutive n per reg)
#pragma unroll
        for (int mi = 0; mi < 4; ++mi)
#pragma unroll
          for (int nj = 0; nj < 4; ++nj)
            acc[mi][nj] = __builtin_amdgcn_mfma_f32_16x16x32_f16(bf[nj], af[mi], acc[mi][nj], 0, 0, 0);
      }
    }
    __syncthreads();          // all Apan reads of this layer done
    // gated write-back: lane (l15,quad) of tile (mi,nj) holds rows m=mi*16+l15,
    // cols C = wn*64 + nj*16 + quad*4 + r  -> one b64 per (mi,nj)
    const unsigned int* ml = &smask[(l + 1) * 256];
    uint2 mA = *(const uint2*)&ml[l15 * 8 + wn * 2];         // pt = l15
    uint2 mB = *(const uint2*)&ml[(16 + l15) * 8 + wn * 2];  // pt = 16+l15
#pragma unroll
    for (int mi = 0; mi < 4; ++mi) {
      uint2 md = (mi & 1) ? mB : mA;
      int m = mi * 16 + l15;
#pragma unroll
      for (int nj = 0; nj < 4; ++nj) {
        unsigned dw = (nj < 2) ? md.x : md.y;
        int bitbase = (nj & 1) * 16 + quad * 4;
        half4_t v;
#pragma unroll
        for (int r = 0; r < 4; ++r)
          v[r] = ((dw >> (bitbase + r)) & 1) ? (_Float16)acc[mi][nj][r]
                                             : (_Float16)0.f;
        *(half4_t*)&Apan[m * SA + wn * 64 + nj * 16 + quad * 4] = v;
      }
    }
    __syncthreads();
  }

  // ---- finalize: T5 @ Wout via one MFMA chain per wave (rows wn*16..+15)
  {
    floatx4 facc = {0.f, 0.f, 0.f, 0.f};
#pragma unroll
    for (int kc = 0; kc < 8; ++kc) {
      half8_t a = *(const half8_t*)&Apan[(wn * 16 + l15) * SA + kc * 32 + quad * 8];
      half8_t b;
#pragma unroll
      for (int j = 0; j < 8; ++j) {
        int k = kc * 32 + quad * 8 + j;
        b[j] = (l15 < 2) ? (_Float16)Wout[2 * k + l15] : (_Float16)0.f;
      }
      facc = __builtin_amdgcn_mfma_f32_16x16x32_f16(a, b, facc, 0, 0, 0);
    }
    // D[row=quad*4+r][col=l15]: global row = wn*16 + quad*4 + r; col 0 -> psi
    // derivative dot (u/v), col 1 -> p derivative dot (f/g)
    if (l15 < 2) {
#pragma unroll
      for (int r = 0; r < 4; ++r) {
        int row = wn * 16 + quad * 4 + r;
        int pt = p0 + (row & 31);
        float val = facc[r];
        if (l15 == 0) {
          if (row < 32) out[NPTS + pt] = -val;      // v = -psi_x
          else          out[pt] = val;              // u =  psi_y
        } else {
          if (row < 32) out[3 * NPTS + pt] = val;   // f = p_x
          else          out[4 * NPTS + pt] = val;   // g = p_y
        }
      }
    }
  }
}

// ---------------------------------------------------------------- launch
extern "C" void kernel_launch(void* const* d_in, const int* in_sizes, int n_in,
                              void* d_out, int out_size, void* d_ws, size_t ws_size,
                              hipStream_t stream) {
  const float* x = (const float*)d_in[0];
  const float* y = (const float*)d_in[1];
  const float* t = (const float*)d_in[2];
  const float* Win = (const float*)d_in[3];
  const float* b_in = (const float*)d_in[4];
  const float* Wh = (const float*)d_in[5];
  const float* b_h = (const float*)d_in[6];
  const float* Wout = (const float*)d_in[7];
  const float* b_out = (const float*)d_in[8];
  float* out = (float*)d_out;

  char* ws = (char*)d_ws;
  constexpr size_t MASK_SZ = (size_t)NPTS * 32;       // 2 MB per layer
  unsigned char* masks = (unsigned char*)ws;
  _Float16* Wt = (_Float16*)(ws + 5 * MASK_SZ);

  // weight transpose/cast first (independent of fwd)
  prep_weights_kernel<<<1024, 256, 0, stream>>>(Wh, Wt);

  // fp32 np-exact forward: masks L0..L4 + p
  fwd_fused_kernel<<<NPTS / 128, 1024, 0, stream>>>(
      x, y, t, Win, b_in, Wh, b_h, Wout, b_out, masks, out);

  // fused tangent chain: init + 4 MFMA layers + finalize (u,v,f,g)
  tangent_fused_kernel<<<NPTS / 32, 256, 0, stream>>>(
      Win, Wt, (const unsigned int*)masks, Wout, out);
}